// Round 6
// baseline (476.032 us; speedup 1.0000x reference)
//
#include <hip/hip_runtime.h>
#include <hip/hip_bf16.h>

// Int8Linear: out[M,N] = (x[M,K] fp32) x (w[N,K] int8-in-int32)^T * scale[N]
// Round 6: i8 path, 32x32x32 MFMA (4404 TOPS vs 3944 for 16x16x64), merged
// 3-barrier/K-tile schedule (was 4), full-128B-line C stores (32x32 C layout).
// Geometry unchanged from r5: 256x256, BK=128 i8, 128-B LDS rows, chunk^row&7
// swizzle via pre-swizzled global source, counted lgkm/vm waits.

#define M_DIM 8192
#define N_DIM 11008
#define K_DIM 4096

#define BM 256
#define BN 256
#define BK 128   // int8 elems -> 128 B per LDS row, 32 K-tiles

using f32x4  = __attribute__((ext_vector_type(4))) float;
using i32x4  = __attribute__((ext_vector_type(4))) int;
using i32x16 = __attribute__((ext_vector_type(16))) int;
using s16x4  = __attribute__((ext_vector_type(4))) short;
using s16x8  = __attribute__((ext_vector_type(8))) short;

typedef __attribute__((address_space(3))) void lds_void_t;
typedef __attribute__((address_space(1))) const void gbl_void_t;

__device__ __forceinline__ short cvt_bf16(float f) {
    union { float f; unsigned u; } v; v.f = f;
    unsigned r = v.u + 0x7fffu + ((v.u >> 16) & 1u);  // RNE
    return (short)(r >> 16);
}

// ---- prepass: per-row symmetric int8 quantization of x ----
__global__ __launch_bounds__(256) void quant_x(const float* __restrict__ X,
                                               signed char* __restrict__ Q,
                                               float* __restrict__ sx) {
    const int row = blockIdx.x;
    const int tid = threadIdx.x;
    const f32x4* xr = (const f32x4*)(X + (size_t)row * K_DIM);

    f32x4 v[4];
    float m = 0.f;
    #pragma unroll
    for (int i = 0; i < 4; ++i) {
        v[i] = xr[tid * 4 + i];
        #pragma unroll
        for (int j = 0; j < 4; ++j) m = fmaxf(m, fabsf(v[i][j]));
    }
    #pragma unroll
    for (int off = 32; off; off >>= 1) m = fmaxf(m, __shfl_xor(m, off));
    __shared__ float wmax[4];
    if ((tid & 63) == 0) wmax[tid >> 6] = m;
    __syncthreads();
    m = fmaxf(fmaxf(wmax[0], wmax[1]), fmaxf(wmax[2], wmax[3]));

    const float inv = (m > 0.f) ? 127.0f / m : 0.f;
    i32x4 o;
    #pragma unroll
    for (int i = 0; i < 4; ++i) {
        int b0 = __float2int_rn(v[i][0] * inv) & 255;
        int b1 = __float2int_rn(v[i][1] * inv) & 255;
        int b2 = __float2int_rn(v[i][2] * inv) & 255;
        int b3 = __float2int_rn(v[i][3] * inv) & 255;
        o[i] = b0 | (b1 << 8) | (b2 << 16) | (b3 << 24);
    }
    ((i32x4*)(Q + (size_t)row * K_DIM))[tid] = o;
    if (tid == 0) sx[row] = (m > 0.f) ? m * (1.0f / 127.0f) : 0.f;
}

// ---- prepass: int32 weights -> packed int8 (exact) ----
__global__ __launch_bounds__(256) void convert_w(const int* __restrict__ W,
                                                 signed char* __restrict__ Q, int n16) {
    int i = blockIdx.x * blockDim.x + threadIdx.x;
    const int stride = gridDim.x * blockDim.x;
    for (; i < n16; i += stride) {
        i32x4 o;
        #pragma unroll
        for (int j = 0; j < 4; ++j) {
            i32x4 v = ((const i32x4*)W)[i * 4 + j];
            o[j] = (v[0] & 255) | ((v[1] & 255) << 8) | ((v[2] & 255) << 16) | (v[3] << 24);
        }
        ((i32x4*)Q)[i] = o;
    }
}

#define SBAR __builtin_amdgcn_s_barrier()
#define LGKM(n) do { asm volatile("s_waitcnt lgkmcnt(" #n ")" ::: "memory"); \
                     __builtin_amdgcn_sched_barrier(0); } while (0)
#define WAIT_VM(n) do { asm volatile("s_waitcnt vmcnt(" #n ")" ::: "memory"); \
                        __builtin_amdgcn_sched_barrier(0); } while (0)

// Stage one operand tile (256 rows x 128 B = 32 KB): 4 gload_lds x 512 thr x 16 B.
// LDS dest LINEAR; bank swizzle via pre-swizzled global source chunk (jl).
#define STAGE(bufi, opi, srcp, T) do {                                             \
    signed char* _d = &lds[bufi][opi][0];                                          \
    const size_t _toff = (size_t)((T) & 31) * 128;                                 \
    _Pragma("unroll")                                                              \
    for (int _i = 0; _i < 4; ++_i)                                                 \
        __builtin_amdgcn_global_load_lds(                                          \
            (gbl_void_t*)((srcp) + (size_t)_i * 64 * K_DIM + _toff),               \
            (lds_void_t*)(_d + (_i * 512 + tid) * 16), 16, 0, 0);                  \
} while (0)

// Read A quadrant qm: 2 frags of 32 rows x 4 ksteps = 8 x ds_read_b128, swizzled.
// 32x32x32 i8 A layout: lane l holds row = l&31, k = (l>>5)*16 + j.
// byte = row*128 + ((ks*2 + l5) ^ (row&7))*16, row&7 = l31&7.
#define READ_A(dst, bufi, qm) do {                                                 \
    const signed char* _s = &lds[bufi][0][0];                                      \
    _Pragma("unroll")                                                              \
    for (int _f = 0; _f < 2; ++_f)                                                 \
        _Pragma("unroll")                                                          \
        for (int _k = 0; _k < 4; ++_k)                                             \
            dst[_f][_k] = *(const i32x4*)(_s                                       \
                + (size_t)((mi * 128 + (qm) * 64 + _f * 32 + l31) * 128)           \
                + ((((_k << 1) | l5) ^ l7) << 4));                                 \
} while (0)

// Read B quadrant qn: 1 frag of 32 cols x 4 ksteps = 4 x ds_read_b128, swizzled.
#define READ_B(dst, bufi, qn) do {                                                 \
    const signed char* _s = &lds[bufi][1][0];                                      \
    _Pragma("unroll")                                                              \
    for (int _k = 0; _k < 4; ++_k)                                                 \
        dst[_k] = *(const i32x4*)(_s                                               \
            + (size_t)((ni * 64 + (qn) * 32 + l31) * 128)                          \
            + ((((_k << 1) | l5) ^ l7) << 4));                                     \
} while (0)

// 8 x mfma_i32_32x32x32_i8: quadrant (qm: 2 m-frags) x (qn: 1 n-frag) x 4 ksteps.
#define MFMA_Q(qm, qn, aset, bset) do {                                            \
    __builtin_amdgcn_s_setprio(1);                                                 \
    _Pragma("unroll")                                                              \
    for (int _f = 0; _f < 2; ++_f)                                                 \
        _Pragma("unroll")                                                          \
        for (int _k = 0; _k < 4; ++_k)                                             \
            acc[(qm) * 2 + _f][qn] = __builtin_amdgcn_mfma_i32_32x32x32_i8(        \
                aset[_f][_k], bset[_k], acc[(qm) * 2 + _f][qn], 0, 0, 0);          \
    __builtin_amdgcn_s_setprio(0);                                                 \
} while (0)

// Merged 3-phase K-tile (ledger verified):
// P1: +12 reads (B q1, A q1 of T); LGKM(12) [drains T q0 reads] -> q00;
//     LGKM(8) [drains B q1] -> q01; SBAR.   (8 A-reads outstanding)
// P2: STAGE B(T+2); LGKM(0) -> a1 ready -> q11; VM(4) [drains tile T+1,
//     leaves B(T+2) in flight]; SBAR.       (T+1 fully in LDS for P3)
// P3: STAGE A(T+2); +12 reads (T+1 q0 from OBUF); LGKM(12) no-op; q10; SBAR.
// Region safety: B(T) last read P1, covered by LGKM(8) pre-barrier, staged P2.
//                A(T) last read P1, covered by LGKM(0)@P2 pre-barrier, staged P3.
#define HALF_ITER(BUF, OBUF, BQ0, BQ1, T) do {                                     \
    READ_B(BQ1, BUF, 1);                                                           \
    READ_A(a1, BUF, 1);                                                            \
    LGKM(12);                                                                      \
    MFMA_Q(0, 0, a0, BQ0);                                                         \
    LGKM(8);                                                                       \
    MFMA_Q(0, 1, a0, BQ1);                                                         \
    SBAR;                                                                          \
    STAGE(BUF, 1, Bsrc, (T) + 2);                                                  \
    LGKM(0);                                                                       \
    MFMA_Q(1, 1, a1, BQ1);                                                         \
    WAIT_VM(4);                                                                    \
    SBAR;                                                                          \
    STAGE(BUF, 0, Asrc, (T) + 2);                                                  \
    READ_A(a0, OBUF, 0);                                                           \
    READ_B(BQ1, OBUF, 0);                                                          \
    LGKM(12);                                                                      \
    MFMA_Q(1, 0, a1, BQ0);                                                         \
    SBAR;                                                                          \
} while (0)

__global__ __launch_bounds__(512, 2) void gemm_i8(
    const signed char* __restrict__ A,   // [M, K] int8 (quantized x)
    const signed char* __restrict__ B,   // [N, K] int8 (weights)
    const float* __restrict__ sx,        // [M] row scales of x
    const float* __restrict__ scale,     // [N] channel scales of w
    float*       __restrict__ C)         // [M, N]
{
    __shared__ __align__(16) signed char lds[2][2][256 * 128];  // 128 KiB

    const int tid  = threadIdx.x;
    const int lane = tid & 63;
    const int l31  = lane & 31;
    const int l5   = lane >> 5;
    const int l7   = l31 & 7;
    const int wave = tid >> 6;
    const int mi   = wave >> 2;   // 0..1: A half (128-row block)
    const int ni   = wave & 3;    // 0..3: 64-col block

    // XCD-chunked bijective swizzle: 1376 = 8 x 172; per XCD: 4 bm x 43 bn.
    const int bid = blockIdx.x;
    const int xcd = bid & 7;
    const int idx = bid >> 3;
    const int bm  = xcd * 4 + (idx & 3);  // 0..31
    const int bn  = idx >> 2;             // 0..42

    // Pre-swizzled staging source: chunk c = i*512+tid -> row = i*64+(tid>>3),
    // src chunk = (tid&7) ^ (row&7) = (tid&7) ^ ((tid>>3)&7).  (bytes)
    const int jl   = (tid & 7) ^ ((tid >> 3) & 7);
    const int soff = (tid >> 3) * K_DIM + jl * 16;
    const signed char* Asrc = A + (size_t)bm * BM * K_DIM + soff;
    const signed char* Bsrc = B + (size_t)bn * BN * K_DIM + soff;

    i32x16 acc[4][2] = {};          // [m-frag 32 rows][n-frag 32 cols]
    i32x4  a0[2][4], a1[2][4];      // [frag][kstep]
    i32x4  b_a[4], b_b[4];          // [kstep]

    STAGE(0, 1, Bsrc, 0);
    STAGE(0, 0, Asrc, 0);
    STAGE(1, 1, Bsrc, 1);
    STAGE(1, 0, Asrc, 1);
    WAIT_VM(8);
    SBAR;
    READ_A(a0, 0, 0);   // 12 outstanding entering P1, matching steady state
    READ_B(b_a, 0, 0);

    for (int it = 0; it < 16; ++it) {
        const int t0 = 2 * it;
        HALF_ITER(0, 1, b_a, b_b, t0);      // tile t0   (buf0)
        HALF_ITER(1, 0, b_b, b_a, t0 + 1);  // tile t0+1 (buf1)
    }

    // Epilogue (32x32 C/D layout: col = lane&31, row = (reg&3)+8*(reg>>2)+4*l5):
    // every store: lanes 0-31 = one full 128-B line, lanes 32-63 = line at row+4.
    const int row0 = bm * BM + mi * 128 + l5 * 4;
    const int col0 = bn * BN + ni * 64 + l31;
    #pragma unroll
    for (int am = 0; am < 4; ++am) {
        const int rb = row0 + am * 32;
        float sxv[16];
        #pragma unroll
        for (int reg = 0; reg < 16; ++reg)
            sxv[reg] = sx[rb + (reg & 3) + 8 * (reg >> 2)];
        #pragma unroll
        for (int an = 0; an < 2; ++an) {
            const int cb = col0 + an * 32;
            const float sc_v = scale[cb];
            #pragma unroll
            for (int reg = 0; reg < 16; ++reg) {
                const int r = rb + (reg & 3) + 8 * (reg >> 2);
                __builtin_nontemporal_store(
                    (float)acc[am][an][reg] * sxv[reg] * sc_v,
                    &C[(size_t)r * N_DIM + cb]);
            }
        }
    }
}

// ---- fallback (round-1 fused bf16 kernel) if ws is too small ----
#define FBM 128
#define FBN 128
#define FBK 32
#define LDK 40
__global__ __launch_bounds__(256) void int8_linear_fused(
    const float* __restrict__ A, const int* __restrict__ W,
    const float* __restrict__ scale, float* __restrict__ C)
{
    __shared__ short As[FBM][LDK];
    __shared__ short Bs[FBN][LDK];
    const int tid = threadIdx.x;
    const int bid = blockIdx.x;
    const int g   = bid / (8 * 86);
    const int rem = bid % (8 * 86);
    const int bm  = g * 8 + (rem & 7);
    const int bn  = rem >> 3;
    const int srow = tid >> 3;
    const int skq  = tid & 7;
    const float* Ab = A + (size_t)(bm * FBM + srow) * K_DIM + skq * 4;
    const int*   Wb = W + (size_t)(bn * FBN + srow) * K_DIM + skq * 4;
    const int lane = tid & 63, wave = tid >> 6;
    const int wm = (wave >> 1) * 64, wn = (wave & 1) * 64;
    const int fr = lane & 15, fq = lane >> 4;
    f32x4 acc[4][4] = {};
    f32x4 areg[4]; i32x4 breg[4];
    #pragma unroll
    for (int i = 0; i < 4; ++i) {
        areg[i] = *(const f32x4*)(Ab + (size_t)(i * 32) * K_DIM);
        breg[i] = *(const i32x4*)(Wb + (size_t)(i * 32) * K_DIM);
    }
    const int NT = K_DIM / FBK;
    for (int kt = 0; kt < NT; ++kt) {
        __syncthreads();
        #pragma unroll
        for (int i = 0; i < 4; ++i) {
            s16x4 av, bv;
            #pragma unroll
            for (int j = 0; j < 4; ++j) {
                av[j] = cvt_bf16(areg[i][j]);
                bv[j] = cvt_bf16((float)breg[i][j]);
            }
            *(s16x4*)&As[srow + i * 32][skq * 4] = av;
            *(s16x4*)&Bs[srow + i * 32][skq * 4] = bv;
        }
        __syncthreads();
        if (kt + 1 < NT) {
            const int k0 = (kt + 1) * FBK;
            #pragma unroll
            for (int i = 0; i < 4; ++i) {
                areg[i] = *(const f32x4*)(Ab + (size_t)(i * 32) * K_DIM + k0);
                breg[i] = *(const i32x4*)(Wb + (size_t)(i * 32) * K_DIM + k0);
            }
        }
        s16x8 af[4], bf[4];
        #pragma unroll
        for (int m = 0; m < 4; ++m) af[m] = *(const s16x8*)&As[wm + m * 16 + fr][fq * 8];
        #pragma unroll
        for (int n = 0; n < 4; ++n) bf[n] = *(const s16x8*)&Bs[wn + n * 16 + fr][fq * 8];
        #pragma unroll
        for (int m = 0; m < 4; ++m)
            #pragma unroll
            for (int n = 0; n < 4; ++n)
                acc[m][n] = __builtin_amdgcn_mfma_f32_16x16x32_bf16(af[m], bf[n], acc[m][n], 0, 0, 0);
    }
    #pragma unroll
    for (int n = 0; n < 4; ++n) {
        const int gn = bn * FBN + wn + n * 16 + fr;
        const float s = scale[gn];
        #pragma unroll
        for (int m = 0; m < 4; ++m) {
            const int gm0 = bm * FBM + wm + m * 16 + fq * 4;
            #pragma unroll
            for (int j = 0; j < 4; ++j)
                C[(size_t)(gm0 + j) * N_DIM + gn] = acc[m][n][j] * s;
        }
    }
}

extern "C" void kernel_launch(void* const* d_in, const int* in_sizes, int n_in,
                              void* d_out, int out_size, void* d_ws, size_t ws_size,
                              hipStream_t stream) {
    const float* x  = (const float*)d_in[0];
    const int*   w  = (const int*)d_in[1];
    const float* sc = (const float*)d_in[2];
    float* out = (float*)d_out;

    const size_t w_bytes  = (size_t)N_DIM * K_DIM;
    const size_t x_bytes  = (size_t)M_DIM * K_DIM;
    const size_t sx_bytes = (size_t)M_DIM * sizeof(float);
    const size_t need = w_bytes + x_bytes + sx_bytes;

    if (ws_size >= need) {
        signed char* qw = (signed char*)d_ws;
        signed char* qx = qw + w_bytes;
        float* sx = (float*)(qx + x_bytes);
        convert_w<<<dim3(2048), dim3(256), 0, stream>>>(w, qw, (int)(w_bytes / 16));
        quant_x<<<dim3(M_DIM), dim3(256), 0, stream>>>(x, qx, sx);
        const int nblocks = (M_DIM / BM) * (N_DIM / BN);  // 1376
        gemm_i8<<<dim3(nblocks), dim3(512), 0, stream>>>(qx, qw, sx, sc, out);
    } else {
        const int nblocks = (M_DIM / FBM) * (N_DIM / FBN);
        int8_linear_fused<<<dim3(nblocks), dim3(256), 0, stream>>>(x, w, sc, out);
    }
}

// Round 7
// 418.362 us; speedup vs baseline: 1.1378x; 1.1378x over previous
//
#include <hip/hip_runtime.h>
#include <hip/hip_bf16.h>

// Int8Linear: out[M,N] = (x[M,K] fp32) x (w[N,K] int8-in-int32)^T * scale[N]
// Round 7: r5's 16x16x64 i8 kernel (zero-conflict fragment addressing) with a
// rebalanced schedule:
//   - one MFMA cluster per phase (q00|q01|q11|q10), reads issued >=1 phase ahead
//   - LDS read issue spread 12/0/8/4 across phases (r5 was 12/8/0/12 with a
//     same-phase LGKM(0) stall at P2)
//   - stages at P3 (B) / P4 (A), after each region's natural all-wave drain
//   - ONE vm wait per tile, draining only tile T+1 (issued 4-6 phases prior)
//   - 3 barriers per tile (end P1/P2/P3)
//   - epilogue: 4 consecutive stores complete each 256-B row segment (write combine)

#define M_DIM 8192
#define N_DIM 11008
#define K_DIM 4096

#define BM 256
#define BN 256
#define BK 128   // int8 elems -> 128 B per LDS row, 32 K-tiles

using f32x4  = __attribute__((ext_vector_type(4))) float;
using i32x4  = __attribute__((ext_vector_type(4))) int;
using s16x4  = __attribute__((ext_vector_type(4))) short;
using s16x8  = __attribute__((ext_vector_type(8))) short;

typedef __attribute__((address_space(3))) void lds_void_t;
typedef __attribute__((address_space(1))) const void gbl_void_t;

__device__ __forceinline__ short cvt_bf16(float f) {
    union { float f; unsigned u; } v; v.f = f;
    unsigned r = v.u + 0x7fffu + ((v.u >> 16) & 1u);  // RNE
    return (short)(r >> 16);
}

// ---- prepass: per-row symmetric int8 quantization of x ----
__global__ __launch_bounds__(256) void quant_x(const float* __restrict__ X,
                                               signed char* __restrict__ Q,
                                               float* __restrict__ sx) {
    const int row = blockIdx.x;
    const int tid = threadIdx.x;
    const f32x4* xr = (const f32x4*)(X + (size_t)row * K_DIM);

    f32x4 v[4];
    float m = 0.f;
    #pragma unroll
    for (int i = 0; i < 4; ++i) {
        v[i] = xr[tid * 4 + i];
        #pragma unroll
        for (int j = 0; j < 4; ++j) m = fmaxf(m, fabsf(v[i][j]));
    }
    #pragma unroll
    for (int off = 32; off; off >>= 1) m = fmaxf(m, __shfl_xor(m, off));
    __shared__ float wmax[4];
    if ((tid & 63) == 0) wmax[tid >> 6] = m;
    __syncthreads();
    m = fmaxf(fmaxf(wmax[0], wmax[1]), fmaxf(wmax[2], wmax[3]));

    const float inv = (m > 0.f) ? 127.0f / m : 0.f;
    i32x4 o;
    #pragma unroll
    for (int i = 0; i < 4; ++i) {
        int b0 = __float2int_rn(v[i][0] * inv) & 255;
        int b1 = __float2int_rn(v[i][1] * inv) & 255;
        int b2 = __float2int_rn(v[i][2] * inv) & 255;
        int b3 = __float2int_rn(v[i][3] * inv) & 255;
        o[i] = b0 | (b1 << 8) | (b2 << 16) | (b3 << 24);
    }
    ((i32x4*)(Q + (size_t)row * K_DIM))[tid] = o;
    if (tid == 0) sx[row] = (m > 0.f) ? m * (1.0f / 127.0f) : 0.f;
}

// ---- prepass: int32 weights -> packed int8 (exact) ----
__global__ __launch_bounds__(256) void convert_w(const int* __restrict__ W,
                                                 signed char* __restrict__ Q, int n16) {
    int i = blockIdx.x * blockDim.x + threadIdx.x;
    const int stride = gridDim.x * blockDim.x;
    for (; i < n16; i += stride) {
        i32x4 o;
        #pragma unroll
        for (int j = 0; j < 4; ++j) {
            i32x4 v = ((const i32x4*)W)[i * 4 + j];
            o[j] = (v[0] & 255) | ((v[1] & 255) << 8) | ((v[2] & 255) << 16) | (v[3] << 24);
        }
        ((i32x4*)Q)[i] = o;
    }
}

#define SBAR __builtin_amdgcn_s_barrier()
#define LGKM(n) do { asm volatile("s_waitcnt lgkmcnt(" #n ")" ::: "memory"); \
                     __builtin_amdgcn_sched_barrier(0); } while (0)
#define WAIT_VM(n) do { asm volatile("s_waitcnt vmcnt(" #n ")" ::: "memory"); \
                        __builtin_amdgcn_sched_barrier(0); } while (0)

// Stage one operand tile (256 rows x 128 B = 32 KB): 4 gload_lds x 512 thr x 16 B.
// LDS dest LINEAR; bank swizzle via pre-swizzled global source chunk (jl).
#define STAGE(bufi, opi, srcp, T) do {                                             \
    signed char* _d = &lds[bufi][opi][0];                                          \
    const size_t _toff = (size_t)((T) & 31) * 128;                                 \
    _Pragma("unroll")                                                              \
    for (int _i = 0; _i < 4; ++_i)                                                 \
        __builtin_amdgcn_global_load_lds(                                          \
            (gbl_void_t*)((srcp) + (size_t)_i * 64 * K_DIM + _toff),               \
            (lds_void_t*)(_d + (_i * 512 + tid) * 16), 16, 0, 0);                  \
} while (0)

// Read A quadrant qm: 4 m-frags x 2 k-steps = 8 x ds_read_b128 (r5 addressing,
// measured zero-conflict). byte = row*128 + ((chunk ^ (row&7))<<4), chunk=(k<<2)|fq.
#define READ_A(dst, bufi, qm) do {                                                 \
    const signed char* _s = &lds[bufi][0][0];                                      \
    _Pragma("unroll")                                                              \
    for (int _m = 0; _m < 4; ++_m)                                                 \
        _Pragma("unroll")                                                          \
        for (int _k = 0; _k < 2; ++_k)                                             \
            dst[_m][_k] = *(const i32x4*)(_s                                       \
                + (size_t)((mi * 128 + (qm) * 64 + _m * 16 + fr) * 128)            \
                + ((((_k << 2) | fq) ^ fr7) << 4));                                \
} while (0)

// Read B quadrant qn: 2 n-frags x 2 k-steps = 4 x ds_read_b128.
#define READ_B(dst, bufi, qn) do {                                                 \
    const signed char* _s = &lds[bufi][1][0];                                      \
    _Pragma("unroll")                                                              \
    for (int _n = 0; _n < 2; ++_n)                                                 \
        _Pragma("unroll")                                                          \
        for (int _k = 0; _k < 2; ++_k)                                             \
            dst[_n][_k] = *(const i32x4*)(_s                                       \
                + (size_t)((ni * 64 + (qn) * 32 + _n * 16 + fr) * 128)             \
                + ((((_k << 2) | fq) ^ fr7) << 4));                                \
} while (0)

#define MFMA_Q(qm, qn, aset, bset) do {                                            \
    __builtin_amdgcn_s_setprio(1);                                                 \
    _Pragma("unroll")                                                              \
    for (int _m = 0; _m < 4; ++_m)                                                 \
        _Pragma("unroll")                                                          \
        for (int _n = 0; _n < 2; ++_n)                                             \
            _Pragma("unroll")                                                      \
            for (int _k = 0; _k < 2; ++_k)                                         \
                acc[(qm) * 4 + _m][(qn) * 2 + _n] =                                \
                    __builtin_amdgcn_mfma_i32_16x16x64_i8(                         \
                        aset[_m][_k], bset[_n][_k],                                \
                        acc[(qm) * 4 + _m][(qn) * 2 + _n], 0, 0, 0);               \
    __builtin_amdgcn_s_setprio(0);                                                 \
} while (0)

// Tile T from BUF; OBUF holds tile T+1.  B0 = b0(T) regs (loaded P4 of T-1);
// B0N receives b0(T+1).  a0(T) loaded P3 of T-1; a1(T),b1(T) loaded here (P1).
//
// LGKM ledger (outstanding ds ops, oldest first):
//  enter P1: [a0' 8, b0' 4] =12 ; P1 +12 -> LGKM(12) drains a0',b0' (this tile's
//  a0,b0; issued 1-2 phases ago under q11/q10).  Remaining [b1 4, a1 8].
//  P2: q01 needs b1 -> compiler auto lgkm(8) (b1 one phase old, hidden by q00+bar).
//  P3: +8 (a0 of T+1) -> LGKM(8) drains a1 (two phases old).  Remaining [a0' 8].
//  P4: +4 (b0 of T+1) -> 12 = steady state.
// VM ledger: stages B(T+2)@P3, A(T+2)@P4.  At P2-end in flight = exactly
//  B(T+1)@P3(T-1) + A(T+1)@P4(T-1); VM(0) drains them (issued 4-6 phases prior,
//  ~free) -> OBUF reads at P3/P4 safe after the end-P2 barrier.
// Region safety (3 barriers: end P1/P2/P3):
//  stage B(T+2)@P3: BUF.B last reads = b1@P2 (compiler lgkm pre-end-P2 bar) and
//    b0@P4(T-1) (drained P1 LGKM(12) pre-end-P1 bar). safe.
//  stage A(T+2)@P4: BUF.A last reads = a1@P3 (LGKM(8) pre-end-P3 bar) and
//    a0@P1/P2 (drained by P1 LGKM(12)). safe.
//  OBUF stages next occur at P3(T+1), after end-P2(T+1) barrier => ordered after
//    every wave's P3/P4(T) OBUF reads.
#define HALF_ITER(BUF, OBUF, B0, B0N, T) do {                                      \
    /* P1: cluster q00 = a0 x b0 */                                                \
    READ_B(b1, BUF, 1);                                                            \
    READ_A(a1, BUF, 1);                                                            \
    LGKM(12);                                                                      \
    MFMA_Q(0, 0, a0, B0);                                                          \
    SBAR;                                                                          \
    /* P2: cluster q01 = a0 x b1 (compiler waits b1); drain T+1 stages */          \
    MFMA_Q(0, 1, a0, b1);                                                          \
    WAIT_VM(0);                                                                    \
    SBAR;                                                                          \
    /* P3: cluster q11 = a1 x b1; stage B(T+2); prefetch a0(T+1) */                \
    STAGE(BUF, 1, Bsrc, (T) + 2);                                                  \
    READ_A(a0, OBUF, 0);                                                           \
    LGKM(8);                                                                       \
    MFMA_Q(1, 1, a1, b1);                                                          \
    SBAR;                                                                          \
    /* P4: cluster q10 = a1 x b0; stage A(T+2); prefetch b0(T+1); no barrier */    \
    STAGE(BUF, 0, Asrc, (T) + 2);                                                  \
    READ_B(B0N, OBUF, 0);                                                          \
    MFMA_Q(1, 0, a1, B0);                                                          \
} while (0)

__global__ __launch_bounds__(512, 2) void gemm_i8(
    const signed char* __restrict__ A,   // [M, K] int8 (quantized x)
    const signed char* __restrict__ B,   // [N, K] int8 (weights)
    const float* __restrict__ sx,        // [M] row scales of x
    const float* __restrict__ scale,     // [N] channel scales of w
    float*       __restrict__ C)         // [M, N]
{
    __shared__ __align__(16) signed char lds[2][2][256 * 128];  // 128 KiB

    const int tid  = threadIdx.x;
    const int lane = tid & 63;
    const int fr   = lane & 15;
    const int fq   = lane >> 4;
    const int fr7  = fr & 7;
    const int wave = tid >> 6;
    const int mi   = wave >> 2;   // 0..1: A half (128-row block)
    const int ni   = wave & 3;    // 0..3: 64-col block

    // XCD-chunked bijective swizzle: 1376 = 8 x 172; per XCD: 4 bm x 43 bn.
    const int bid = blockIdx.x;
    const int xcd = bid & 7;
    const int idx = bid >> 3;
    const int bm  = xcd * 4 + (idx & 3);  // 0..31
    const int bn  = idx >> 2;             // 0..42

    // Pre-swizzled staging source: chunk c = i*512+tid -> row = i*64+(tid>>3),
    // src chunk = (tid&7) ^ (row&7) = (tid&7) ^ ((tid>>3)&7).  (bytes)
    const int jl   = (tid & 7) ^ ((tid >> 3) & 7);
    const int soff = (tid >> 3) * K_DIM + jl * 16;
    const signed char* Asrc = A + (size_t)bm * BM * K_DIM + soff;
    const signed char* Bsrc = B + (size_t)bn * BN * K_DIM + soff;

    i32x4 acc[8][4] = {};
    i32x4 a0[4][2], a1[4][2];            // A quadrants of current tile
    i32x4 b0e[2][2], b0o[2][2], b1[2][2];// b0 rotates per tile parity; b1 per-tile

    // Prologue: stage tiles 0,1; wait tile 0; pre-issue a0(T0), b0(T0).
    STAGE(0, 1, Bsrc, 0);
    STAGE(0, 0, Asrc, 0);
    STAGE(1, 1, Bsrc, 1);
    STAGE(1, 0, Asrc, 1);
    WAIT_VM(8);
    SBAR;
    READ_A(a0, 0, 0);   // 8
    READ_B(b0e, 0, 0);  // 4  -> 12 outstanding = steady state
    for (int it = 0; it < 16; ++it) {
        const int t0 = 2 * it;
        HALF_ITER(0, 1, b0e, b0o, t0);      // tile t0   (buf0)
        HALF_ITER(1, 0, b0o, b0e, t0 + 1);  // tile t0+1 (buf1)
    }

    // Epilogue: per (i,jj) row, the 4 jn-stores are consecutive instructions
    // covering cols col0+{0,16,32,48} -> 256 B of the row, NT write-combinable.
    const int row0 = bm * BM + mi * 128 + fq * 4;
    const int col0 = bn * BN + ni * 64 + fr;
    float s4[4];
    #pragma unroll
    for (int jn = 0; jn < 4; ++jn) s4[jn] = scale[col0 + jn * 16];
    #pragma unroll
    for (int i = 0; i < 8; ++i) {
        #pragma unroll
        for (int jj = 0; jj < 4; ++jj) {
            const int r = row0 + i * 16 + jj;
            const float sxv = sx[r];
            #pragma unroll
            for (int jn = 0; jn < 4; ++jn)
                __builtin_nontemporal_store(
                    (float)acc[i][jn][jj] * sxv * s4[jn],
                    &C[(size_t)r * N_DIM + col0 + jn * 16]);
        }
    }
}

// ---- fallback (round-1 fused bf16 kernel) if ws is too small ----
#define FBM 128
#define FBN 128
#define FBK 32
#define LDK 40
__global__ __launch_bounds__(256) void int8_linear_fused(
    const float* __restrict__ A, const int* __restrict__ W,
    const float* __restrict__ scale, float* __restrict__ C)
{
    __shared__ short As[FBM][LDK];
    __shared__ short Bs[FBN][LDK];
    const int tid = threadIdx.x;
    const int bid = blockIdx.x;
    const int g   = bid / (8 * 86);
    const int rem = bid % (8 * 86);
    const int bm  = g * 8 + (rem & 7);
    const int bn  = rem >> 3;
    const int srow = tid >> 3;
    const int skq  = tid & 7;
    const float* Ab = A + (size_t)(bm * FBM + srow) * K_DIM + skq * 4;
    const int*   Wb = W + (size_t)(bn * FBN + srow) * K_DIM + skq * 4;
    const int lane = tid & 63, wave = tid >> 6;
    const int wm = (wave >> 1) * 64, wn = (wave & 1) * 64;
    const int fr = lane & 15, fq = lane >> 4;
    f32x4 acc[4][4] = {};
    f32x4 areg[4]; i32x4 breg[4];
    #pragma unroll
    for (int i = 0; i < 4; ++i) {
        areg[i] = *(const f32x4*)(Ab + (size_t)(i * 32) * K_DIM);
        breg[i] = *(const i32x4*)(Wb + (size_t)(i * 32) * K_DIM);
    }
    const int NT = K_DIM / FBK;
    for (int kt = 0; kt < NT; ++kt) {
        __syncthreads();
        #pragma unroll
        for (int i = 0; i < 4; ++i) {
            s16x4 av, bv;
            #pragma unroll
            for (int j = 0; j < 4; ++j) {
                av[j] = cvt_bf16(areg[i][j]);
                bv[j] = cvt_bf16((float)breg[i][j]);
            }
            *(s16x4*)&As[srow + i * 32][skq * 4] = av;
            *(s16x4*)&Bs[srow + i * 32][skq * 4] = bv;
        }
        __syncthreads();
        if (kt + 1 < NT) {
            const int k0 = (kt + 1) * FBK;
            #pragma unroll
            for (int i = 0; i < 4; ++i) {
                areg[i] = *(const f32x4*)(Ab + (size_t)(i * 32) * K_DIM + k0);
                breg[i] = *(const i32x4*)(Wb + (size_t)(i * 32) * K_DIM + k0);
            }
        }
        s16x8 af[4], bf[4];
        #pragma unroll
        for (int m = 0; m < 4; ++m) af[m] = *(const s16x8*)&As[wm + m * 16 + fr][fq * 8];
        #pragma unroll
        for (int n = 0; n < 4; ++n) bf[n] = *(const s16x8*)&Bs[wn + n * 16 + fr][fq * 8];
        #pragma unroll
        for (int m = 0; m < 4; ++m)
            #pragma unroll
            for (int n = 0; n < 4; ++n)
                acc[m][n] = __builtin_amdgcn_mfma_f32_16x16x32_bf16(af[m], bf[n], acc[m][n], 0, 0, 0);
    }
    #pragma unroll
    for (int n = 0; n < 4; ++n) {
        const int gn = bn * FBN + wn + n * 16 + fr;
        const float s = scale[gn];
        #pragma unroll
        for (int m = 0; m < 4; ++m) {
            const int gm0 = bm * FBM + wm + m * 16 + fq * 4;
            #pragma unroll
            for (int j = 0; j < 4; ++j)
                C[(size_t)(gm0 + j) * N_DIM + gn] = acc[m][n][j] * s;
        }
    }
}

extern "C" void kernel_launch(void* const* d_in, const int* in_sizes, int n_in,
                              void* d_out, int out_size, void* d_ws, size_t ws_size,
                              hipStream_t stream) {
    const float* x  = (const float*)d_in[0];
    const int*   w  = (const int*)d_in[1];
    const float* sc = (const float*)d_in[2];
    float* out = (float*)d_out;

    const size_t w_bytes  = (size_t)N_DIM * K_DIM;
    const size_t x_bytes  = (size_t)M_DIM * K_DIM;
    const size_t sx_bytes = (size_t)M_DIM * sizeof(float);
    const size_t need = w_bytes + x_bytes + sx_bytes;

    if (ws_size >= need) {
        signed char* qw = (signed char*)d_ws;
        signed char* qx = qw + w_bytes;
        float* sx = (float*)(qx + x_bytes);
        convert_w<<<dim3(2048), dim3(256), 0, stream>>>(w, qw, (int)(w_bytes / 16));
        quant_x<<<dim3(M_DIM), dim3(256), 0, stream>>>(x, qx, sx);
        const int nblocks = (M_DIM / BM) * (N_DIM / BN);  // 1376
        gemm_i8<<<dim3(nblocks), dim3(512), 0, stream>>>(qx, qw, sx, sc, out);
    } else {
        const int nblocks = (M_DIM / FBM) * (N_DIM / FBN);
        int8_linear_fused<<<dim3(nblocks), dim3(256), 0, stream>>>(x, w, sc, out);
    }
}